// Round 1
// baseline (1063.390 us; speedup 1.0000x reference)
//
#include <hip/hip_runtime.h>
#include <hip/hip_bf16.h>
#include <math.h>

// ---------------- constants (problem is fixed-shape) ----------------
// B=2, H=W=256, L=65536, C=180, NH=6, hd=30, WS=8, hd_ffn=360
// I/O dtype: fp32 (per reference). Internals: bf16 (MFMA), fp32 accum.
#define BATCH 2
#define IMG 256
#define LTOK 65536
#define CH 180
#define BL (BATCH * LTOK)            // 131072 tokens
#define HDF 360

using frag_ab = __attribute__((ext_vector_type(8))) short;   // 8 bf16 in 4 VGPRs
using frag_cd = __attribute__((ext_vector_type(4))) float;   // 4 f32 acc

__device__ __forceinline__ float b2f(unsigned short u) {
    union { unsigned int i; float f; } v; v.i = ((unsigned int)u) << 16; return v.f;
}
__device__ __forceinline__ float blo(unsigned int u) {
    union { unsigned int i; float f; } v; v.i = u << 16; return v.f;
}
__device__ __forceinline__ float bhi(unsigned int u) {
    union { unsigned int i; float f; } v; v.i = u & 0xffff0000u; return v.f;
}
__device__ __forceinline__ unsigned short f2b(float f) {
    union { float f; unsigned int i; } v; v.f = f;
    unsigned int x = v.i;
    unsigned int r = (x + 0x7fffu + ((x >> 16) & 1u)) >> 16;   // RNE
    return (unsigned short)r;
}
__device__ __forceinline__ float gelu_f(float x) {
    return 0.5f * x * (1.0f + erff(x * 0.70710678118654752f));
}

// row-index permutations for window attention, folded into GEMM epilogues.
// PERM=1: token-order row -> window-order position. PERM=2: inverse.
template <int PERM>
__device__ __forceinline__ int perm_row(int row) {
    if (PERM == 1) {
        int b = row >> 16, l = row & 65535;
        int y = l >> 8, x = l & 255;
        return (b << 16) + ((((y >> 3) << 5) + (x >> 3)) << 6) + ((y & 7) << 3) + (x & 7);
    } else if (PERM == 2) {
        int b = row >> 16, wv = row & 65535;
        int wid = wv >> 6, t = wv & 63;
        int wy = wid >> 5, wx = wid & 31;
        return (b << 16) + ((((wy << 3) + (t >> 3))) << 8) + (wx << 3) + (t & 7);
    }
    return row;
}

// ---------------- one-shot weight prep ----------------
__global__ __launch_bounds__(256) void convw_kernel(
    const float* __restrict__ a, const float* __restrict__ b,
    const float* __restrict__ c, const float* __restrict__ d,
    const float* __restrict__ cdw, const float* __restrict__ fdw,
    unsigned short* __restrict__ wbf, float* __restrict__ wT1, float* __restrict__ wT2)
{
    int g = blockIdx.x * 256 + threadIdx.x;
    if (g < 259200) {
        float v;
        if      (g < 97200)  v = a[g];
        else if (g < 129600) v = b[g - 97200];
        else if (g < 194400) v = c[g - 129600];
        else                 v = d[g - 194400];
        wbf[g] = f2b(v);
    } else if (g < 265680) {
        int i = g - 259200;               // tap-major [9][180]
        int tap = i / 180, ch = i % 180;
        wT1[i] = cdw[ch * 9 + tap];
    } else if (g < 278640) {
        int i = g - 265680;               // [9][360]
        int tap = i / 360, ch = i % 360;
        wT2[i] = fdw[ch * 9 + tap];
    }
}

// ---------------- LayerNorm: one wave per token, vectorized (45 active lanes) ----------------
__device__ __forceinline__ void ld4(const float* p, float v[4]) {
    float4 t = *(const float4*)p; v[0]=t.x; v[1]=t.y; v[2]=t.z; v[3]=t.w;
}
__device__ __forceinline__ void ld4(const unsigned short* p, float v[4]) {
    ushort4 t = *(const ushort4*)p; v[0]=b2f(t.x); v[1]=b2f(t.y); v[2]=b2f(t.z); v[3]=b2f(t.w);
}

template <typename TIN>
__global__ __launch_bounds__(256) void ln_kernel(
    const TIN* __restrict__ x, const float* __restrict__ g,
    const float* __restrict__ bta, unsigned short* __restrict__ out)
{
    int wave = threadIdx.x >> 6, lane = threadIdx.x & 63;
    int tok = blockIdx.x * 4 + wave;
    const bool act = lane < 45;                 // 45*4 = 180 channels
    float v[4] = {0.f, 0.f, 0.f, 0.f};
    const TIN* row = x + (size_t)tok * CH;
    if (act) ld4(row + lane * 4, v);
    float s  = v[0] + v[1] + v[2] + v[3];
    float sq = v[0]*v[0] + v[1]*v[1] + v[2]*v[2] + v[3]*v[3];
    #pragma unroll
    for (int off = 32; off > 0; off >>= 1) {
        s  += __shfl_xor(s, off);
        sq += __shfl_xor(sq, off);
    }
    float mean = s * (1.f / CH);
    float var  = sq * (1.f / CH) - mean * mean;
    float rstd = rsqrtf(var + 1e-5f);
    if (act) {
        float4 gg = *(const float4*)&g[lane * 4];
        float4 bb = *(const float4*)&bta[lane * 4];
        unsigned int o0 = (unsigned int)f2b((v[0]-mean)*rstd*gg.x + bb.x)
                        | ((unsigned int)f2b((v[1]-mean)*rstd*gg.y + bb.y) << 16);
        unsigned int o1 = (unsigned int)f2b((v[2]-mean)*rstd*gg.z + bb.z)
                        | ((unsigned int)f2b((v[3]-mean)*rstd*gg.w + bb.w) << 16);
        *(uint2*)(out + (size_t)tok * CH + lane * 4) = make_uint2(o0, o1);
    }
}

// ---------------- generic MFMA GEMM (+ optional row-perm epilogue) ----------------
__device__ __forceinline__ void stv(float* p, float v) { *p = v; }
__device__ __forceinline__ void stv(unsigned short* p, float v) { *p = f2b(v); }

template <int ACT, bool HAS_BIAS, bool HAS_RES, int PERM, typename TOUT>
__global__ __launch_bounds__(256) void gemm_kernel(
    const unsigned short* __restrict__ X, int ldx,
    const unsigned short* __restrict__ Wt,
    const float* __restrict__ bias,
    const unsigned short* __restrict__ res, int ldr,
    TOUT* __restrict__ Y, int ldy,
    int N, int K)
{
    __shared__ unsigned short Xs[64][40];
    __shared__ unsigned short Ws[64][40];
    const int tid = threadIdx.x;
    const int wave = tid >> 6;
    const int lane = tid & 63;
    const int l16 = lane & 15;
    const int q = lane >> 4;
    const int m0 = blockIdx.x * 64;
    const int n0 = blockIdx.y * 64;
    const int lr = tid >> 2;
    const int lk = (tid & 3) << 3;

    frag_cd acc[4];
    #pragma unroll
    for (int i = 0; i < 4; ++i) acc[i] = (frag_cd){0.f, 0.f, 0.f, 0.f};

    for (int k0 = 0; k0 < K; k0 += 32) {
        const bool kfull = (k0 + 32 <= K);
        {
            const unsigned short* p = X + (size_t)(m0 + lr) * ldx + (k0 + lk);
            if (kfull) {
                *(uint2*)&Xs[lr][lk]     = *(const uint2*)p;
                *(uint2*)&Xs[lr][lk + 4] = *(const uint2*)(p + 4);
            } else {
                #pragma unroll
                for (int j = 0; j < 8; ++j)
                    Xs[lr][lk + j] = (k0 + lk + j < K) ? p[j] : (unsigned short)0;
            }
        }
        {
            const int n = n0 + lr;
            const unsigned short* p = Wt + (size_t)n * K + (k0 + lk);
            if (n < N && kfull) {
                *(uint2*)&Ws[lr][lk]     = *(const uint2*)p;
                *(uint2*)&Ws[lr][lk + 4] = *(const uint2*)(p + 4);
            } else {
                #pragma unroll
                for (int j = 0; j < 8; ++j)
                    Ws[lr][lk + j] = (n < N && (k0 + lk + j) < K) ? p[j] : (unsigned short)0;
            }
        }
        __syncthreads();
        frag_ab bfr = *(const frag_ab*)&Ws[wave * 16 + l16][q * 8];
        #pragma unroll
        for (int mb = 0; mb < 4; ++mb) {
            frag_ab afr = *(const frag_ab*)&Xs[mb * 16 + l16][q * 8];
            acc[mb] = __builtin_amdgcn_mfma_f32_16x16x32_bf16(afr, bfr, acc[mb], 0, 0, 0);
        }
        __syncthreads();
    }
    const int col = n0 + wave * 16 + l16;
    if (col < N) {
        float bv = 0.f;
        if (HAS_BIAS) bv = bias[col];
        #pragma unroll
        for (int mb = 0; mb < 4; ++mb) {
            #pragma unroll
            for (int r = 0; r < 4; ++r) {
                int row = m0 + mb * 16 + q * 4 + r;
                int orow = perm_row<PERM>(row);
                float v = acc[mb][r] + bv;
                if (ACT == 1) v = gelu_f(v);
                if (HAS_RES) v += b2f(res[(size_t)orow * ldr + col]);
                stv(&Y[(size_t)orow * ldy + col], v);
            }
        }
    }
}

// ---------------- window attention: one wave per (window, head) ----------------
// qkvw is WINDOW-ORDERED: row w64 = w*64 + t, cols [q:h*30+d][k:180+...][v:360+...]
// attn_out written window-ordered [BL][180].
// Thread i owns query row i: S-row (64 fp32) in registers -> softmax thread-local.
// k then v staged via one shared f32 buffer (broadcast reads, conflict-free).
__global__ __launch_bounds__(64) void attn_kernel(
    const unsigned short* __restrict__ qkvw,
    const float* __restrict__ b_rel,
    unsigned short* __restrict__ attn_out)
{
    __shared__ float kv[64][36];            // 9216 B; stride 36 floats (144 B, 16B-aligned rows)
    const int blk = blockIdx.x;             // 0..12287
    const int h = blk % 6;
    const int w = blk / 6;                  // 0..2047; row base = w*64 (window-ordered)
    const int lane = threadIdx.x;
    const float scale = 0.18257418583505536f;  // 30^-0.5

    const unsigned short* qrow = qkvw + (size_t)(w * 64 + lane) * 540 + h * 30;

    // q row -> registers (fp32)
    float q[30];
    #pragma unroll
    for (int d = 0; d < 15; ++d) {
        unsigned int u = *(const unsigned int*)(qrow + 2 * d);
        q[2 * d] = blo(u); q[2 * d + 1] = bhi(u);
    }
    // k row -> LDS (fp32)
    #pragma unroll
    for (int d = 0; d < 15; ++d) {
        unsigned int u = *(const unsigned int*)(qrow + 180 + 2 * d);
        kv[lane][2 * d] = blo(u); kv[lane][2 * d + 1] = bhi(u);
    }
    __syncthreads();

    // S row in registers
    float s[64];
    const float* br = b_rel + h * 4096 + lane * 64;
    #pragma unroll
    for (int j = 0; j < 64; ++j) {
        const float* kj = &kv[j][0];
        float acc = 0.f;
        #pragma unroll
        for (int d = 0; d < 30; ++d) acc += q[d] * kj[d];
        s[j] = acc * scale + br[j];
    }

    // thread-local softmax (unnormalized; fold 1/sum into output)
    float mx = -1e30f;
    #pragma unroll
    for (int j = 0; j < 64; ++j) mx = fmaxf(mx, s[j]);
    float sum = 0.f;
    #pragma unroll
    for (int j = 0; j < 64; ++j) { s[j] = __expf(s[j] - mx); sum += s[j]; }
    float inv = 1.f / sum;

    // v row -> LDS (reuse buffer)
    __syncthreads();
    #pragma unroll
    for (int d = 0; d < 15; ++d) {
        unsigned int u = *(const unsigned int*)(qrow + 360 + 2 * d);
        kv[lane][2 * d] = blo(u); kv[lane][2 * d + 1] = bhi(u);
    }
    __syncthreads();

    // O row = (P @ V) * inv
    float o[30];
    #pragma unroll
    for (int d = 0; d < 30; ++d) o[d] = 0.f;
    #pragma unroll
    for (int j = 0; j < 64; ++j) {
        const float* vj = &kv[j][0];
        float p = s[j];
        #pragma unroll
        for (int d = 0; d < 30; ++d) o[d] += p * vj[d];
    }
    unsigned short* orow = attn_out + (size_t)(w * 64 + lane) * CH + h * 30;
    #pragma unroll
    for (int d = 0; d < 15; ++d) {
        unsigned int u = (unsigned int)f2b(o[2 * d] * inv)
                       | ((unsigned int)f2b(o[2 * d + 1] * inv) << 16);
        *(unsigned int*)(orow + 2 * d) = u;
    }
}

// ---------------- depthwise 3x3 SAME conv, vectorized column-walk ----------------
template <int C, bool DO_GELU>
__global__ __launch_bounds__(256) void dwconv_kernel(
    const unsigned short* __restrict__ in, const float* __restrict__ wT,
    unsigned short* __restrict__ out)
{
    constexpr int NG = (C + 7) / 8;
    constexpr int TY = 8;
    int gid = blockIdx.x * 256 + threadIdx.x;
    int cg = gid % NG;
    int t  = gid / NG;
    int x  = t % IMG;
    int t2 = t / IMG;
    int yb = t2 & 31;
    int bi = t2 >> 5;
    if (bi >= BATCH) return;
    const int c0 = cg * 8;
    const int y0 = yb * TY;

    float w9[9][8];
    #pragma unroll
    for (int tp = 0; tp < 9; ++tp) {
        float4 wa = *(const float4*)&wT[tp * C + c0];
        float4 wb = *(const float4*)&wT[tp * C + c0 + 4];
        w9[tp][0]=wa.x; w9[tp][1]=wa.y; w9[tp][2]=wa.z; w9[tp][3]=wa.w;
        w9[tp][4]=wb.x; w9[tp][5]=wb.y; w9[tp][6]=wb.z; w9[tp][7]=wb.w;
    }

    unsigned int rr[3][3][4];

    auto load_row = [&](int y, unsigned int dst[3][4]) {
        if ((unsigned)y >= (unsigned)IMG) {
            #pragma unroll
            for (int cc = 0; cc < 3; ++cc)
                #pragma unroll
                for (int k = 0; k < 4; ++k) dst[cc][k] = 0u;
            return;
        }
        size_t base = ((size_t)((bi << 16) + (y << 8) + x)) * C + c0;
        #pragma unroll
        for (int cc = 0; cc < 3; ++cc) {
            int xx = x + cc - 1;
            if ((unsigned)xx >= (unsigned)IMG) {
                dst[cc][0] = dst[cc][1] = dst[cc][2] = dst[cc][3] = 0u;
                continue;
            }
            const unsigned short* p = in + base + (ptrdiff_t)(cc - 1) * C;
            uint2 u0 = *(const uint2*)p;
            uint2 u1 = *(const uint2*)(p + 4);
            dst[cc][0] = u0.x; dst[cc][1] = u0.y; dst[cc][2] = u1.x; dst[cc][3] = u1.y;
        }
    };

    load_row(y0 - 1, rr[0]);
    load_row(y0,     rr[1]);

    #pragma unroll
    for (int dy = 0; dy < TY; ++dy) {
        load_row(y0 + dy + 1, rr[(dy + 2) % 3]);
        float acc[8];
        #pragma unroll
        for (int j = 0; j < 8; ++j) acc[j] = 0.f;
        #pragma unroll
        for (int ky = 0; ky < 3; ++ky) {
            unsigned int (*row)[4] = rr[(dy + ky) % 3];
            #pragma unroll
            for (int kx = 0; kx < 3; ++kx) {
                const float* wp = w9[ky * 3 + kx];
                const unsigned int* u = row[kx];
                acc[0] += blo(u[0]) * wp[0];
                acc[1] += bhi(u[0]) * wp[1];
                acc[2] += blo(u[1]) * wp[2];
                acc[3] += bhi(u[1]) * wp[3];
                acc[4] += blo(u[2]) * wp[4];
                acc[5] += bhi(u[2]) * wp[5];
                acc[6] += blo(u[3]) * wp[6];
                acc[7] += bhi(u[3]) * wp[7];
            }
        }
        if (DO_GELU) {
            #pragma unroll
            for (int j = 0; j < 8; ++j) acc[j] = gelu_f(acc[j]);
        }
        size_t ob = ((size_t)((bi << 16) + ((y0 + dy) << 8) + x)) * C + c0;
        unsigned int o0 = (unsigned int)f2b(acc[0]) | ((unsigned int)f2b(acc[1]) << 16);
        unsigned int o1 = (unsigned int)f2b(acc[2]) | ((unsigned int)f2b(acc[3]) << 16);
        *(uint2*)(out + ob) = make_uint2(o0, o1);
        if (c0 + 8 <= C) {
            unsigned int o2 = (unsigned int)f2b(acc[4]) | ((unsigned int)f2b(acc[5]) << 16);
            unsigned int o3 = (unsigned int)f2b(acc[6]) | ((unsigned int)f2b(acc[7]) << 16);
            *(uint2*)(out + ob + 4) = make_uint2(o2, o3);
        }
    }
}

// ---------------- sum-pool over L per (b,c), ushort4 ----------------
__global__ __launch_bounds__(64) void pool_kernel(
    const unsigned short* __restrict__ cf, float* __restrict__ pooled)
{
    int t = threadIdx.x;
    if (t >= 45) return;
    int b = blockIdx.x >> 7;
    int chunk = blockIdx.x & 127;
    const unsigned short* base = cf + (size_t)(b * LTOK + chunk * 512) * CH + t * 4;
    float s0 = 0.f, s1 = 0.f, s2 = 0.f, s3 = 0.f;
    for (int i = 0; i < 512; ++i) {
        ushort4 v = *(const ushort4*)(base + (size_t)i * CH);
        s0 += b2f(v.x); s1 += b2f(v.y); s2 += b2f(v.z); s3 += b2f(v.w);
    }
    atomicAdd(&pooled[b * CH + t * 4 + 0], s0);
    atomicAdd(&pooled[b * CH + t * 4 + 1], s1);
    atomicAdd(&pooled[b * CH + t * 4 + 2], s2);
    atomicAdd(&pooled[b * CH + t * 4 + 3], s3);
}

// ---------------- channel gate ----------------
__global__ __launch_bounds__(256) void cm_kernel(
    const float* __restrict__ pooled, const float* __restrict__ w1,
    const float* __restrict__ w2, float* __restrict__ cm)
{
    __shared__ float p[BATCH][CH];
    __shared__ float g1[BATCH][22];
    int t = threadIdx.x;
    for (int idx = t; idx < BATCH * CH; idx += 256)
        p[idx / CH][idx % CH] = pooled[idx] * (1.f / (float)LTOK);
    __syncthreads();
    if (t < BATCH * 22) {
        int b = t / 22, u = t % 22;
        float s = 0.f;
        for (int c = 0; c < CH; ++c) s += p[b][c] * w1[u * CH + c];
        g1[b][u] = gelu_f(s);
    }
    __syncthreads();
    for (int idx = t; idx < BATCH * CH; idx += 256) {
        int b = idx / CH, c = idx % CH;
        float s = 0.f;
        for (int u = 0; u < 22; ++u) s += g1[b][u] * w2[c * 22 + u];
        cm[idx] = 1.f / (1.f + __expf(-s));
    }
}

// ---------------- residual 1, 4 channels/thread ----------------
__global__ __launch_bounds__(256) void resid_kernel(
    const float* __restrict__ x, const unsigned short* __restrict__ attn_feat,
    const unsigned short* __restrict__ conv_feat, const float* __restrict__ cm,
    unsigned short* __restrict__ x_mid)
{
    int gid = blockIdx.x * 256 + threadIdx.x;     // BL*CH/4 threads
    int c4 = gid % 45;
    int b = gid / (LTOK * 45);
    float4 xv = ((const float4*)x)[gid];
    ushort4 a = ((const ushort4*)attn_feat)[gid];
    ushort4 c = ((const ushort4*)conv_feat)[gid];
    float4 m = *(const float4*)&cm[b * CH + c4 * 4];
    unsigned int o0 = (unsigned int)f2b(xv.x + b2f(a.x) * m.x + b2f(c.x))
                    | ((unsigned int)f2b(xv.y + b2f(a.y) * m.y + b2f(c.y)) << 16);
    unsigned int o1 = (unsigned int)f2b(xv.z + b2f(a.z) * m.z + b2f(c.z))
                    | ((unsigned int)f2b(xv.w + b2f(a.w) * m.w + b2f(c.w)) << 16);
    ((uint2*)x_mid)[gid] = make_uint2(o0, o1);
}

// ---------------- launch ----------------
extern "C" void kernel_launch(void* const* d_in, const int* in_sizes, int n_in,
                              void* d_out, int out_size, void* d_ws, size_t ws_size,
                              hipStream_t stream)
{
    const float* x       = (const float*)d_in[0];
    const float* w_qkv   = (const float*)d_in[1];
    const float* b_rel   = (const float*)d_in[2];
    const float* w_proj  = (const float*)d_in[3];
    const float* b_proj  = (const float*)d_in[4];
    const float* conv_dw = (const float*)d_in[5];
    const float* cg_w1   = (const float*)d_in[6];
    const float* cg_w2   = (const float*)d_in[7];
    const float* ffn_w1  = (const float*)d_in[8];
    const float* ffn_dw  = (const float*)d_in[9];
    const float* ffn_w2  = (const float*)d_in[10];
    const float* n1_g    = (const float*)d_in[11];
    const float* n1_b    = (const float*)d_in[12];
    const float* n2_g    = (const float*)d_in[13];
    const float* n2_b    = (const float*)d_in[14];

    // ---- workspace layout (bytes), peak ~225.6 MiB ----
    char* ws = (char*)d_ws;
    unsigned short* n1        = (unsigned short*)(ws);                      // [0, 47.2MB)
    unsigned short* qkvw      = (unsigned short*)(ws + 47185920);           // [47.2, 188.7MB) window-ordered
    unsigned short* conv_feat = (unsigned short*)(ws + 188743680);          // [188.7, 235.9MB)
    unsigned short* attn_out  = (unsigned short*)(ws);                      // reuse n1 (window-ordered)
    unsigned short* attn_feat = (unsigned short*)(ws + 47185920);           // reuse qkv head (token order)
    unsigned short* x_mid     = (unsigned short*)(ws + 94371840);           // reuse qkv mid
    unsigned short* n2        = (unsigned short*)(ws + 141557760);          // reuse qkv tail
    unsigned short* h         = (unsigned short*)(ws);                      // [0, 94.4MB)
    unsigned short* h_s       = (unsigned short*)(ws + 141557760);          // [141.6, 235.9MB)
    float*          pooled    = (float*)(ws + 235929600);                   // 1440 B
    float*          cmv       = (float*)(ws + 235931040);                   // 1440 B
    unsigned short* wbf       = (unsigned short*)(ws + 235932480);          // 518,400 B
    float*          wT1       = (float*)(ws + 236450880);                   // 25,920 B
    float*          wT2       = (float*)(ws + 236476800);                   // 51,840 B
    unsigned short* wqkv_b  = wbf;
    unsigned short* wproj_b = wbf + 97200;
    unsigned short* wffn1_b = wbf + 129600;
    unsigned short* wffn2_b = wbf + 194400;
    float* out = (float*)d_out;

    hipMemsetAsync(pooled, 0, 2880, stream);

    // 0. weight prep
    convw_kernel<<<1089, 256, 0, stream>>>(w_qkv, w_proj, ffn_w1, ffn_w2,
                                           conv_dw, ffn_dw, wbf, wT1, wT2);
    // 1. LN1: x(fp32) -> n1(bf16)
    ln_kernel<float><<<BL / 4, 256, 0, stream>>>(x, n1_g, n1_b, n1);
    // 2. qkvw = n1 @ w_qkv^T, rows stored window-ordered (PERM=1)
    gemm_kernel<0, false, false, 1, unsigned short><<<dim3(BL / 64, 9), 256, 0, stream>>>(
        n1, CH, wqkv_b, nullptr, nullptr, 0, qkvw, 540, 540, CH);
    // 3. conv branch: gelu(dwconv3x3(n1)) -> conv_feat
    dwconv_kernel<CH, true><<<1472, 256, 0, stream>>>(n1, wT1, conv_feat);
    // 4. pooled = sum_L conv_feat
    pool_kernel<<<BATCH * 128, 64, 0, stream>>>(conv_feat, pooled);
    // 5. cm
    cm_kernel<<<1, 256, 0, stream>>>(pooled, cg_w1, cg_w2, cmv);
    // 6. window attention: one wave per (window, head)
    attn_kernel<<<2048 * 6, 64, 0, stream>>>(qkvw, b_rel, attn_out);
    // 7. attn_feat = attn_out @ w_proj^T + b_proj; X window-ordered, Y token order (PERM=2)
    gemm_kernel<0, true, false, 2, unsigned short><<<dim3(BL / 64, 3), 256, 0, stream>>>(
        attn_out, CH, wproj_b, b_proj, nullptr, 0, attn_feat, CH, CH, CH);
    // 8. x_mid = x + attn_feat*cm + conv_feat  (bf16)
    resid_kernel<<<(BL * CH / 4) / 256, 256, 0, stream>>>(x, attn_feat, conv_feat, cmv, x_mid);
    // 9. LN2
    ln_kernel<unsigned short><<<BL / 4, 256, 0, stream>>>(x_mid, n2_g, n2_b, n2);
    // 10. h = gelu(n2 @ ffn_w1^T)
    gemm_kernel<1, false, false, 0, unsigned short><<<dim3(BL / 64, 6), 256, 0, stream>>>(
        n2, CH, wffn1_b, nullptr, nullptr, 0, h, HDF, HDF, CH);
    // 11. h_s = dwconv3x3(h)
    dwconv_kernel<HDF, false><<<2880, 256, 0, stream>>>(h, wT2, h_s);
    // 12. out(fp32) = x_mid + h_s @ ffn_w2^T
    gemm_kernel<0, false, true, 0, float><<<dim3(BL / 64, 3), 256, 0, stream>>>(
        h_s, HDF, wffn2_b, nullptr, x_mid, CH, out, CH, CH, HDF);
}

// Round 2
// 952.520 us; speedup vs baseline: 1.1164x; 1.1164x over previous
//
#include <hip/hip_runtime.h>
#include <hip/hip_bf16.h>
#include <math.h>

// ---------------- constants (problem is fixed-shape) ----------------
// B=2, H=W=256, L=65536, C=180, NH=6, hd=30, WS=8, hd_ffn=360
// I/O dtype: fp32 (per reference). Internals: bf16 (MFMA), fp32 accum.
#define BATCH 2
#define IMG 256
#define LTOK 65536
#define CH 180
#define BL (BATCH * LTOK)            // 131072 tokens
#define HDF 360

using frag_ab = __attribute__((ext_vector_type(8))) short;   // 8 bf16 in 4 VGPRs
using frag_cd = __attribute__((ext_vector_type(4))) float;   // 4 f32 acc

__device__ __forceinline__ float b2f(unsigned short u) {
    union { unsigned int i; float f; } v; v.i = ((unsigned int)u) << 16; return v.f;
}
__device__ __forceinline__ float blo(unsigned int u) {
    union { unsigned int i; float f; } v; v.i = u << 16; return v.f;
}
__device__ __forceinline__ float bhi(unsigned int u) {
    union { unsigned int i; float f; } v; v.i = u & 0xffff0000u; return v.f;
}
__device__ __forceinline__ unsigned short f2b(float f) {
    union { float f; unsigned int i; } v; v.f = f;
    unsigned int x = v.i;
    unsigned int r = (x + 0x7fffu + ((x >> 16) & 1u)) >> 16;   // RNE
    return (unsigned short)r;
}
__device__ __forceinline__ float gelu_f(float x) {
    return 0.5f * x * (1.0f + erff(x * 0.70710678118654752f));
}

// row-index permutations for window attention, folded into GEMM epilogues.
// PERM=1: token-order row -> window-order position. PERM=2: inverse.
template <int PERM>
__device__ __forceinline__ int perm_row(int row) {
    if (PERM == 1) {
        int b = row >> 16, l = row & 65535;
        int y = l >> 8, x = l & 255;
        return (b << 16) + ((((y >> 3) << 5) + (x >> 3)) << 6) + ((y & 7) << 3) + (x & 7);
    } else if (PERM == 2) {
        int b = row >> 16, wv = row & 65535;
        int wid = wv >> 6, t = wv & 63;
        int wy = wid >> 5, wx = wid & 31;
        return (b << 16) + ((((wy << 3) + (t >> 3))) << 8) + (wx << 3) + (t & 7);
    }
    return row;
}

// ---------------- one-shot weight prep ----------------
// wbf: bf16 copies of the 4 GEMM weights. wT1/wT2: tap-major dwconv weights.
// br3: b_rel re-ordered to MFMA fragment order per (head, lane):
//      br3[h*4096 + lane*64 + (mt*16+nt*4+r)] = bf16(b_rel[h][mt*16+(lane>>4)*4+r][nt*16+(lane&15)])
__global__ __launch_bounds__(256) void convw_kernel(
    const float* __restrict__ a, const float* __restrict__ b,
    const float* __restrict__ c, const float* __restrict__ d,
    const float* __restrict__ cdw, const float* __restrict__ fdw,
    const float* __restrict__ brel,
    unsigned short* __restrict__ wbf, float* __restrict__ wT1, float* __restrict__ wT2,
    unsigned short* __restrict__ br3)
{
    int g = blockIdx.x * 256 + threadIdx.x;
    if (g < 259200) {
        float v;
        if      (g < 97200)  v = a[g];
        else if (g < 129600) v = b[g - 97200];
        else if (g < 194400) v = c[g - 129600];
        else                 v = d[g - 194400];
        wbf[g] = f2b(v);
    } else if (g < 265680) {
        int i = g - 259200;               // tap-major [9][180]
        int tap = i / 180, ch = i % 180;
        wT1[i] = cdw[ch * 9 + tap];
    } else if (g < 278640) {
        int i = g - 265680;               // [9][360]
        int tap = i / 360, ch = i % 360;
        wT2[i] = fdw[ch * 9 + tap];
    } else if (g < 303216) {
        int i = g - 278640;               // 6*4096 fragment-ordered bias
        int h = i >> 12;
        int rem = i & 4095;
        int lane = rem >> 6;
        int j = rem & 63;
        int mt = j >> 4, nt = (j >> 2) & 3, r = j & 3;
        int row = mt * 16 + (lane >> 4) * 4 + r;
        int col = nt * 16 + (lane & 15);
        br3[i] = f2b(brel[h * 4096 + row * 64 + col]);
    }
}

// ---------------- LayerNorm: one wave per token, vectorized (45 active lanes) ----------------
__device__ __forceinline__ void ld4(const float* p, float v[4]) {
    float4 t = *(const float4*)p; v[0]=t.x; v[1]=t.y; v[2]=t.z; v[3]=t.w;
}
__device__ __forceinline__ void ld4(const unsigned short* p, float v[4]) {
    ushort4 t = *(const ushort4*)p; v[0]=b2f(t.x); v[1]=b2f(t.y); v[2]=b2f(t.z); v[3]=b2f(t.w);
}

template <typename TIN>
__global__ __launch_bounds__(256) void ln_kernel(
    const TIN* __restrict__ x, const float* __restrict__ g,
    const float* __restrict__ bta, unsigned short* __restrict__ out)
{
    int wave = threadIdx.x >> 6, lane = threadIdx.x & 63;
    int tok = blockIdx.x * 4 + wave;
    const bool act = lane < 45;                 // 45*4 = 180 channels
    float v[4] = {0.f, 0.f, 0.f, 0.f};
    const TIN* row = x + (size_t)tok * CH;
    if (act) ld4(row + lane * 4, v);
    float s  = v[0] + v[1] + v[2] + v[3];
    float sq = v[0]*v[0] + v[1]*v[1] + v[2]*v[2] + v[3]*v[3];
    #pragma unroll
    for (int off = 32; off > 0; off >>= 1) {
        s  += __shfl_xor(s, off);
        sq += __shfl_xor(sq, off);
    }
    float mean = s * (1.f / CH);
    float var  = sq * (1.f / CH) - mean * mean;
    float rstd = rsqrtf(var + 1e-5f);
    if (act) {
        float4 gg = *(const float4*)&g[lane * 4];
        float4 bb = *(const float4*)&bta[lane * 4];
        unsigned int o0 = (unsigned int)f2b((v[0]-mean)*rstd*gg.x + bb.x)
                        | ((unsigned int)f2b((v[1]-mean)*rstd*gg.y + bb.y) << 16);
        unsigned int o1 = (unsigned int)f2b((v[2]-mean)*rstd*gg.z + bb.z)
                        | ((unsigned int)f2b((v[3]-mean)*rstd*gg.w + bb.w) << 16);
        *(uint2*)(out + (size_t)tok * CH + lane * 4) = make_uint2(o0, o1);
    }
}

// ---------------- generic MFMA GEMM (+ optional row-perm epilogue) ----------------
__device__ __forceinline__ void stv(float* p, float v) { *p = v; }
__device__ __forceinline__ void stv(unsigned short* p, float v) { *p = f2b(v); }

template <int ACT, bool HAS_BIAS, bool HAS_RES, int PERM, typename TOUT>
__global__ __launch_bounds__(256) void gemm_kernel(
    const unsigned short* __restrict__ X, int ldx,
    const unsigned short* __restrict__ Wt,
    const float* __restrict__ bias,
    const unsigned short* __restrict__ res, int ldr,
    TOUT* __restrict__ Y, int ldy,
    int N, int K)
{
    __shared__ unsigned short Xs[64][40];
    __shared__ unsigned short Ws[64][40];
    const int tid = threadIdx.x;
    const int wave = tid >> 6;
    const int lane = tid & 63;
    const int l16 = lane & 15;
    const int q = lane >> 4;
    const int m0 = blockIdx.x * 64;
    const int n0 = blockIdx.y * 64;
    const int lr = tid >> 2;
    const int lk = (tid & 3) << 3;

    frag_cd acc[4];
    #pragma unroll
    for (int i = 0; i < 4; ++i) acc[i] = (frag_cd){0.f, 0.f, 0.f, 0.f};

    for (int k0 = 0; k0 < K; k0 += 32) {
        const bool kfull = (k0 + 32 <= K);
        {
            const unsigned short* p = X + (size_t)(m0 + lr) * ldx + (k0 + lk);
            if (kfull) {
                *(uint2*)&Xs[lr][lk]     = *(const uint2*)p;
                *(uint2*)&Xs[lr][lk + 4] = *(const uint2*)(p + 4);
            } else {
                #pragma unroll
                for (int j = 0; j < 8; ++j)
                    Xs[lr][lk + j] = (k0 + lk + j < K) ? p[j] : (unsigned short)0;
            }
        }
        {
            const int n = n0 + lr;
            const unsigned short* p = Wt + (size_t)n * K + (k0 + lk);
            if (n < N && kfull) {
                *(uint2*)&Ws[lr][lk]     = *(const uint2*)p;
                *(uint2*)&Ws[lr][lk + 4] = *(const uint2*)(p + 4);
            } else {
                #pragma unroll
                for (int j = 0; j < 8; ++j)
                    Ws[lr][lk + j] = (n < N && (k0 + lk + j) < K) ? p[j] : (unsigned short)0;
            }
        }
        __syncthreads();
        frag_ab bfr = *(const frag_ab*)&Ws[wave * 16 + l16][q * 8];
        #pragma unroll
        for (int mb = 0; mb < 4; ++mb) {
            frag_ab afr = *(const frag_ab*)&Xs[mb * 16 + l16][q * 8];
            acc[mb] = __builtin_amdgcn_mfma_f32_16x16x32_bf16(afr, bfr, acc[mb], 0, 0, 0);
        }
        __syncthreads();
    }
    const int col = n0 + wave * 16 + l16;
    if (col < N) {
        float bv = 0.f;
        if (HAS_BIAS) bv = bias[col];
        #pragma unroll
        for (int mb = 0; mb < 4; ++mb) {
            #pragma unroll
            for (int r = 0; r < 4; ++r) {
                int row = m0 + mb * 16 + q * 4 + r;
                int orow = perm_row<PERM>(row);
                float v = acc[mb][r] + bv;
                if (ACT == 1) v = gelu_f(v);
                if (HAS_RES) v += b2f(res[(size_t)orow * ldr + col]);
                stv(&Y[(size_t)orow * ldy + col], v);
            }
        }
    }
}

// ---------------- window attention: MFMA, one wave per (window, head) ----------------
// qkvw is WINDOW-ORDERED: row w64 = w*64 + t, cols [q:h*30+d][k:180+...][v:360+...]
// S = Q@K^T via mfma_f32_16x16x32_bf16 (A=[m][k] row-chunk pattern, B=[n][k]);
// C/D layout: col=lane&15, row=(lane>>4)*4+reg  (same convention as gemm_kernel).
// Softmax: per-row max/sum via in-register nt-reduce + shfl_xor(1,2,4,8) over the
// 16-lane column group. P (unnormalized bf16) -> LDS; V staged transposed into LDS
// so the PV B-operand is a linear ds_read_b128. 1/sum folded into the O epilogue.
__global__ __launch_bounds__(64) void attn_kernel(
    const unsigned short* __restrict__ qkvw,
    const unsigned short* __restrict__ br3,
    unsigned short* __restrict__ attn_out)
{
    __shared__ unsigned short Pl[64][72];   // P bf16, stride 72 (144 B: 16B-aligned, 2-way banks)
    __shared__ unsigned short VT[32][72];   // V^T bf16 [d][key], rows 30,31 zeroed
    const int blk = blockIdx.x;             // 0..12287
    const int h = blk % 6;
    const int w = blk / 6;
    const int lane = threadIdx.x;
    const int l16 = lane & 15;
    const int g4 = lane >> 4;
    const float scale = 0.18257418583505536f;  // 30^-0.5

    const unsigned short* base = qkvw + (size_t)w * (64 * 540) + h * 30;

    // ---- Q (A) and K (B) fragments straight from global (4B-aligned uint2 loads) ----
    frag_ab qf[4], kf[4];
    #pragma unroll
    for (int t = 0; t < 4; ++t) {
        const unsigned short* pq = base + (size_t)(t * 16 + l16) * 540 + g4 * 8;
        union { frag_ab f; uint2 u[2]; } tq, tk;
        tq.u[0] = *(const uint2*)pq;        tq.u[1] = *(const uint2*)(pq + 4);
        tk.u[0] = *(const uint2*)(pq + 180); tk.u[1] = *(const uint2*)(pq + 184);
        if (g4 == 3) { tk.f[6] = 0; tk.f[7] = 0; }   // zero K pad cols d=30,31
        qf[t] = tq.f; kf[t] = tk.f;
    }

    // ---- fragment-ordered bias (bf16, coalesced uint4 loads) ----
    unsigned int brw[32];
    {
        const unsigned short* bp = br3 + ((size_t)h << 12) + lane * 64;
        #pragma unroll
        for (int c2 = 0; c2 < 8; ++c2)
            *(uint4*)&brw[c2 * 4] = *(const uint4*)(bp + c2 * 8);
    }

    // ---- S = Q @ K^T : 16 MFMA ----
    frag_cd s[4][4];
    #pragma unroll
    for (int mt = 0; mt < 4; ++mt)
        #pragma unroll
        for (int nt = 0; nt < 4; ++nt)
            s[mt][nt] = (frag_cd){0.f, 0.f, 0.f, 0.f};
    #pragma unroll
    for (int mt = 0; mt < 4; ++mt)
        #pragma unroll
        for (int nt = 0; nt < 4; ++nt)
            s[mt][nt] = __builtin_amdgcn_mfma_f32_16x16x32_bf16(qf[mt], kf[nt], s[mt][nt], 0, 0, 0);

    // ---- stage V^T into LDS (overlaps with MFMA latency) ----
    {
        const unsigned short* pv = base + (size_t)lane * 540 + 360;
        #pragma unroll
        for (int d2 = 0; d2 < 15; ++d2) {
            unsigned int u = *(const unsigned int*)(pv + 2 * d2);
            VT[2 * d2][lane]     = (unsigned short)(u & 0xffffu);
            VT[2 * d2 + 1][lane] = (unsigned short)(u >> 16);
        }
        VT[30][lane] = 0; VT[31][lane] = 0;
    }

    // ---- bias + row softmax (unnormalized P -> LDS), inv kept per (mt,reg) ----
    float inv[4][4];
    #pragma unroll
    for (int mt = 0; mt < 4; ++mt) {
        #pragma unroll
        for (int r = 0; r < 4; ++r) {
            float a0 = s[mt][0][r] * scale + (((0 * 4 + r) & 1) ? bhi(brw[(mt * 16 + 0 + r) >> 1]) : blo(brw[(mt * 16 + 0 + r) >> 1]));
            float a1 = s[mt][1][r] * scale + (((1 * 4 + r) & 1) ? bhi(brw[(mt * 16 + 4 + r) >> 1]) : blo(brw[(mt * 16 + 4 + r) >> 1]));
            float a2 = s[mt][2][r] * scale + (((2 * 4 + r) & 1) ? bhi(brw[(mt * 16 + 8 + r) >> 1]) : blo(brw[(mt * 16 + 8 + r) >> 1]));
            float a3 = s[mt][3][r] * scale + (((3 * 4 + r) & 1) ? bhi(brw[(mt * 16 + 12 + r) >> 1]) : blo(brw[(mt * 16 + 12 + r) >> 1]));
            float m = fmaxf(fmaxf(a0, a1), fmaxf(a2, a3));
            m = fmaxf(m, __shfl_xor(m, 1));
            m = fmaxf(m, __shfl_xor(m, 2));
            m = fmaxf(m, __shfl_xor(m, 4));
            m = fmaxf(m, __shfl_xor(m, 8));
            float e0 = __expf(a0 - m), e1 = __expf(a1 - m);
            float e2 = __expf(a2 - m), e3 = __expf(a3 - m);
            float sum = e0 + e1 + e2 + e3;
            sum += __shfl_xor(sum, 1);
            sum += __shfl_xor(sum, 2);
            sum += __shfl_xor(sum, 4);
            sum += __shfl_xor(sum, 8);
            inv[mt][r] = 1.f / sum;
            int row = mt * 16 + g4 * 4 + r;
            Pl[row][l16]      = f2b(e0);
            Pl[row][16 + l16] = f2b(e1);
            Pl[row][32 + l16] = f2b(e2);
            Pl[row][48 + l16] = f2b(e3);
        }
    }
    __syncthreads();

    // ---- O = P @ V : A-frags from Pl, B-frags from VT, 16 MFMA ----
    frag_ab pf[4][2];
    #pragma unroll
    for (int mt = 0; mt < 4; ++mt)
        #pragma unroll
        for (int kt = 0; kt < 2; ++kt)
            pf[mt][kt] = *(const frag_ab*)&Pl[mt * 16 + l16][kt * 32 + g4 * 8];
    frag_ab vf[2][2];
    #pragma unroll
    for (int nt = 0; nt < 2; ++nt)
        #pragma unroll
        for (int kt = 0; kt < 2; ++kt)
            vf[nt][kt] = *(const frag_ab*)&VT[nt * 16 + l16][kt * 32 + g4 * 8];

    frag_cd o[4][2];
    #pragma unroll
    for (int mt = 0; mt < 4; ++mt)
        #pragma unroll
        for (int nt = 0; nt < 2; ++nt)
            o[mt][nt] = (frag_cd){0.f, 0.f, 0.f, 0.f};
    #pragma unroll
    for (int mt = 0; mt < 4; ++mt)
        #pragma unroll
        for (int nt = 0; nt < 2; ++nt)
            #pragma unroll
            for (int kt = 0; kt < 2; ++kt)
                o[mt][nt] = __builtin_amdgcn_mfma_f32_16x16x32_bf16(pf[mt][kt], vf[nt][kt], o[mt][nt], 0, 0, 0);

    // ---- epilogue: normalize rows by inv, store bf16 (cols 30,31 dropped) ----
    unsigned short* ob = attn_out + (size_t)w * (64 * CH) + h * 30;
    #pragma unroll
    for (int mt = 0; mt < 4; ++mt) {
        #pragma unroll
        for (int r = 0; r < 4; ++r) {
            int row = mt * 16 + g4 * 4 + r;
            float iv = inv[mt][r];
            unsigned short* op = ob + (size_t)row * CH;
            op[l16] = f2b(o[mt][0][r] * iv);
            if (l16 < 14) op[16 + l16] = f2b(o[mt][1][r] * iv);
        }
    }
}

// ---------------- depthwise 3x3 SAME conv, vectorized column-walk ----------------
template <int C, bool DO_GELU>
__global__ __launch_bounds__(256) void dwconv_kernel(
    const unsigned short* __restrict__ in, const float* __restrict__ wT,
    unsigned short* __restrict__ out)
{
    constexpr int NG = (C + 7) / 8;
    constexpr int TY = 8;
    int gid = blockIdx.x * 256 + threadIdx.x;
    int cg = gid % NG;
    int t  = gid / NG;
    int x  = t % IMG;
    int t2 = t / IMG;
    int yb = t2 & 31;
    int bi = t2 >> 5;
    if (bi >= BATCH) return;
    const int c0 = cg * 8;
    const int y0 = yb * TY;

    float w9[9][8];
    #pragma unroll
    for (int tp = 0; tp < 9; ++tp) {
        float4 wa = *(const float4*)&wT[tp * C + c0];
        float4 wb = *(const float4*)&wT[tp * C + c0 + 4];
        w9[tp][0]=wa.x; w9[tp][1]=wa.y; w9[tp][2]=wa.z; w9[tp][3]=wa.w;
        w9[tp][4]=wb.x; w9[tp][5]=wb.y; w9[tp][6]=wb.z; w9[tp][7]=wb.w;
    }

    unsigned int rr[3][3][4];

    auto load_row = [&](int y, unsigned int dst[3][4]) {
        if ((unsigned)y >= (unsigned)IMG) {
            #pragma unroll
            for (int cc = 0; cc < 3; ++cc)
                #pragma unroll
                for (int k = 0; k < 4; ++k) dst[cc][k] = 0u;
            return;
        }
        size_t base = ((size_t)((bi << 16) + (y << 8) + x)) * C + c0;
        #pragma unroll
        for (int cc = 0; cc < 3; ++cc) {
            int xx = x + cc - 1;
            if ((unsigned)xx >= (unsigned)IMG) {
                dst[cc][0] = dst[cc][1] = dst[cc][2] = dst[cc][3] = 0u;
                continue;
            }
            const unsigned short* p = in + base + (ptrdiff_t)(cc - 1) * C;
            uint2 u0 = *(const uint2*)p;
            uint2 u1 = *(const uint2*)(p + 4);
            dst[cc][0] = u0.x; dst[cc][1] = u0.y; dst[cc][2] = u1.x; dst[cc][3] = u1.y;
        }
    };

    load_row(y0 - 1, rr[0]);
    load_row(y0,     rr[1]);

    #pragma unroll
    for (int dy = 0; dy < TY; ++dy) {
        load_row(y0 + dy + 1, rr[(dy + 2) % 3]);
        float acc[8];
        #pragma unroll
        for (int j = 0; j < 8; ++j) acc[j] = 0.f;
        #pragma unroll
        for (int ky = 0; ky < 3; ++ky) {
            unsigned int (*row)[4] = rr[(dy + ky) % 3];
            #pragma unroll
            for (int kx = 0; kx < 3; ++kx) {
                const float* wp = w9[ky * 3 + kx];
                const unsigned int* u = row[kx];
                acc[0] += blo(u[0]) * wp[0];
                acc[1] += bhi(u[0]) * wp[1];
                acc[2] += blo(u[1]) * wp[2];
                acc[3] += bhi(u[1]) * wp[3];
                acc[4] += blo(u[2]) * wp[4];
                acc[5] += bhi(u[2]) * wp[5];
                acc[6] += blo(u[3]) * wp[6];
                acc[7] += bhi(u[3]) * wp[7];
            }
        }
        if (DO_GELU) {
            #pragma unroll
            for (int j = 0; j < 8; ++j) acc[j] = gelu_f(acc[j]);
        }
        size_t ob = ((size_t)((bi << 16) + ((y0 + dy) << 8) + x)) * C + c0;
        unsigned int o0 = (unsigned int)f2b(acc[0]) | ((unsigned int)f2b(acc[1]) << 16);
        unsigned int o1 = (unsigned int)f2b(acc[2]) | ((unsigned int)f2b(acc[3]) << 16);
        *(uint2*)(out + ob) = make_uint2(o0, o1);
        if (c0 + 8 <= C) {
            unsigned int o2 = (unsigned int)f2b(acc[4]) | ((unsigned int)f2b(acc[5]) << 16);
            unsigned int o3 = (unsigned int)f2b(acc[6]) | ((unsigned int)f2b(acc[7]) << 16);
            *(uint2*)(out + ob + 4) = make_uint2(o2, o3);
        }
    }
}

// ---------------- sum-pool over L per (b,c), ushort4 ----------------
__global__ __launch_bounds__(64) void pool_kernel(
    const unsigned short* __restrict__ cf, float* __restrict__ pooled)
{
    int t = threadIdx.x;
    if (t >= 45) return;
    int b = blockIdx.x >> 7;
    int chunk = blockIdx.x & 127;
    const unsigned short* base = cf + (size_t)(b * LTOK + chunk * 512) * CH + t * 4;
    float s0 = 0.f, s1 = 0.f, s2 = 0.f, s3 = 0.f;
    for (int i = 0; i < 512; ++i) {
        ushort4 v = *(const ushort4*)(base + (size_t)i * CH);
        s0 += b2f(v.x); s1 += b2f(v.y); s2 += b2f(v.z); s3 += b2f(v.w);
    }
    atomicAdd(&pooled[b * CH + t * 4 + 0], s0);
    atomicAdd(&pooled[b * CH + t * 4 + 1], s1);
    atomicAdd(&pooled[b * CH + t * 4 + 2], s2);
    atomicAdd(&pooled[b * CH + t * 4 + 3], s3);
}

// ---------------- channel gate ----------------
__global__ __launch_bounds__(256) void cm_kernel(
    const float* __restrict__ pooled, const float* __restrict__ w1,
    const float* __restrict__ w2, float* __restrict__ cm)
{
    __shared__ float p[BATCH][CH];
    __shared__ float g1[BATCH][22];
    int t = threadIdx.x;
    for (int idx = t; idx < BATCH * CH; idx += 256)
        p[idx / CH][idx % CH] = pooled[idx] * (1.f / (float)LTOK);
    __syncthreads();
    if (t < BATCH * 22) {
        int b = t / 22, u = t % 22;
        float s = 0.f;
        for (int c = 0; c < CH; ++c) s += p[b][c] * w1[u * CH + c];
        g1[b][u] = gelu_f(s);
    }
    __syncthreads();
    for (int idx = t; idx < BATCH * CH; idx += 256) {
        int b = idx / CH, c = idx % CH;
        float s = 0.f;
        for (int u = 0; u < 22; ++u) s += g1[b][u] * w2[c * 22 + u];
        cm[idx] = 1.f / (1.f + __expf(-s));
    }
}

// ---------------- residual 1, 4 channels/thread ----------------
__global__ __launch_bounds__(256) void resid_kernel(
    const float* __restrict__ x, const unsigned short* __restrict__ attn_feat,
    const unsigned short* __restrict__ conv_feat, const float* __restrict__ cm,
    unsigned short* __restrict__ x_mid)
{
    int gid = blockIdx.x * 256 + threadIdx.x;     // BL*CH/4 threads
    int c4 = gid % 45;
    int b = gid / (LTOK * 45);
    float4 xv = ((const float4*)x)[gid];
    ushort4 a = ((const ushort4*)attn_feat)[gid];
    ushort4 c = ((const ushort4*)conv_feat)[gid];
    float4 m = *(const float4*)&cm[b * CH + c4 * 4];
    unsigned int o0 = (unsigned int)f2b(xv.x + b2f(a.x) * m.x + b2f(c.x))
                    | ((unsigned int)f2b(xv.y + b2f(a.y) * m.y + b2f(c.y)) << 16);
    unsigned int o1 = (unsigned int)f2b(xv.z + b2f(a.z) * m.z + b2f(c.z))
                    | ((unsigned int)f2b(xv.w + b2f(a.w) * m.w + b2f(c.w)) << 16);
    ((uint2*)x_mid)[gid] = make_uint2(o0, o1);
}

// ---------------- launch ----------------
extern "C" void kernel_launch(void* const* d_in, const int* in_sizes, int n_in,
                              void* d_out, int out_size, void* d_ws, size_t ws_size,
                              hipStream_t stream)
{
    const float* x       = (const float*)d_in[0];
    const float* w_qkv   = (const float*)d_in[1];
    const float* b_rel   = (const float*)d_in[2];
    const float* w_proj  = (const float*)d_in[3];
    const float* b_proj  = (const float*)d_in[4];
    const float* conv_dw = (const float*)d_in[5];
    const float* cg_w1   = (const float*)d_in[6];
    const float* cg_w2   = (const float*)d_in[7];
    const float* ffn_w1  = (const float*)d_in[8];
    const float* ffn_dw  = (const float*)d_in[9];
    const float* ffn_w2  = (const float*)d_in[10];
    const float* n1_g    = (const float*)d_in[11];
    const float* n1_b    = (const float*)d_in[12];
    const float* n2_g    = (const float*)d_in[13];
    const float* n2_b    = (const float*)d_in[14];

    // ---- workspace layout (bytes), peak ~225.7 MiB ----
    char* ws = (char*)d_ws;
    unsigned short* n1        = (unsigned short*)(ws);                      // [0, 47.2MB)
    unsigned short* qkvw      = (unsigned short*)(ws + 47185920);           // [47.2, 188.7MB) window-ordered
    unsigned short* conv_feat = (unsigned short*)(ws + 188743680);          // [188.7, 235.9MB)
    unsigned short* attn_out  = (unsigned short*)(ws);                      // reuse n1 (window-ordered)
    unsigned short* attn_feat = (unsigned short*)(ws + 47185920);           // reuse qkv head (token order)
    unsigned short* x_mid     = (unsigned short*)(ws + 94371840);           // reuse qkv mid
    unsigned short* n2        = (unsigned short*)(ws + 141557760);          // reuse qkv tail
    unsigned short* h         = (unsigned short*)(ws);                      // [0, 94.4MB)
    unsigned short* h_s       = (unsigned short*)(ws + 141557760);          // [141.6, 235.9MB)
    float*          pooled    = (float*)(ws + 235929600);                   // 1440 B
    float*          cmv       = (float*)(ws + 235931040);                   // 1440 B
    unsigned short* wbf       = (unsigned short*)(ws + 235932480);          // 518,400 B
    float*          wT1       = (float*)(ws + 236450880);                   // 25,920 B
    float*          wT2       = (float*)(ws + 236476800);                   // 51,840 B
    unsigned short* br3       = (unsigned short*)(ws + 236528640);          // 49,152 B
    unsigned short* wqkv_b  = wbf;
    unsigned short* wproj_b = wbf + 97200;
    unsigned short* wffn1_b = wbf + 129600;
    unsigned short* wffn2_b = wbf + 194400;
    float* out = (float*)d_out;

    hipMemsetAsync(pooled, 0, 2880, stream);

    // 0. weight prep (incl. fragment-ordered bf16 b_rel)
    convw_kernel<<<1185, 256, 0, stream>>>(w_qkv, w_proj, ffn_w1, ffn_w2,
                                           conv_dw, ffn_dw, b_rel, wbf, wT1, wT2, br3);
    // 1. LN1: x(fp32) -> n1(bf16)
    ln_kernel<float><<<BL / 4, 256, 0, stream>>>(x, n1_g, n1_b, n1);
    // 2. qkvw = n1 @ w_qkv^T, rows stored window-ordered (PERM=1)
    gemm_kernel<0, false, false, 1, unsigned short><<<dim3(BL / 64, 9), 256, 0, stream>>>(
        n1, CH, wqkv_b, nullptr, nullptr, 0, qkvw, 540, 540, CH);
    // 3. conv branch: gelu(dwconv3x3(n1)) -> conv_feat
    dwconv_kernel<CH, true><<<1472, 256, 0, stream>>>(n1, wT1, conv_feat);
    // 4. pooled = sum_L conv_feat
    pool_kernel<<<BATCH * 128, 64, 0, stream>>>(conv_feat, pooled);
    // 5. cm
    cm_kernel<<<1, 256, 0, stream>>>(pooled, cg_w1, cg_w2, cmv);
    // 6. window attention (MFMA): one wave per (window, head)
    attn_kernel<<<2048 * 6, 64, 0, stream>>>(qkvw, br3, attn_out);
    // 7. attn_feat = attn_out @ w_proj^T + b_proj; X window-ordered, Y token order (PERM=2)
    gemm_kernel<0, true, false, 2, unsigned short><<<dim3(BL / 64, 3), 256, 0, stream>>>(
        attn_out, CH, wproj_b, b_proj, nullptr, 0, attn_feat, CH, CH, CH);
    // 8. x_mid = x + attn_feat*cm + conv_feat  (bf16)
    resid_kernel<<<(BL * CH / 4) / 256, 256, 0, stream>>>(x, attn_feat, conv_feat, cmv, x_mid);
    // 9. LN2
    ln_kernel<unsigned short><<<BL / 4, 256, 0, stream>>>(x_mid, n2_g, n2_b, n2);
    // 10. h = gelu(n2 @ ffn_w1^T)
    gemm_kernel<1, false, false, 0, unsigned short><<<dim3(BL / 64, 6), 256, 0, stream>>>(
        n2, CH, wffn1_b, nullptr, nullptr, 0, h, HDF, HDF, CH);
    // 11. h_s = dwconv3x3(h)
    dwconv_kernel<HDF, false><<<2880, 256, 0, stream>>>(h, wT2, h_s);
    // 12. out(fp32) = x_mid + h_s @ ffn_w2^T
    gemm_kernel<0, false, true, 0, float><<<dim3(BL / 64, 3), 256, 0, stream>>>(
        h_s, HDF, wffn2_b, nullptr, x_mid, CH, out, CH, CH, HDF);
}